// Round 1
// baseline (689.207 us; speedup 1.0000x reference)
//
#include <hip/hip_runtime.h>

// Problem: out = -weight * sum(factor[1:] * factor[:-1]) / (N-1)
// factor: (N=65536, D=2000) fp32 row-major  =>  sum a[k]*a[k+D], k in [0,(N-1)*D)
// Memory-bound: 524 MB @ ~6.3 TB/s => ~83 us floor.

#define N_ROWS 65536
#define D_COLS 2000

__global__ __launch_bounds__(256) void shifted_dot_kernel(
    const float* __restrict__ a,
    const float* __restrict__ weight,
    float* __restrict__ out,
    long long total4) {
    long long tid    = (long long)blockIdx.x * blockDim.x + threadIdx.x;
    long long stride = (long long)gridDim.x * blockDim.x;

    const float4* a4 = (const float4*)a;
    const long long shift4 = D_COLS / 4;  // 500 float4s = 8000 bytes (16B aligned)

    float acc = 0.0f;
    for (long long k = tid; k < total4; k += stride) {
        float4 x = a4[k];
        float4 y = a4[k + shift4];
        acc += x.x * y.x + x.y * y.y + x.z * y.z + x.w * y.w;
    }

    // wave (64-lane) shuffle reduction
    #pragma unroll
    for (int off = 32; off > 0; off >>= 1)
        acc += __shfl_down(acc, off, 64);

    __shared__ float wave_sums[4];  // 256 threads = 4 waves
    int lane = threadIdx.x & 63;
    int wid  = threadIdx.x >> 6;
    if (lane == 0) wave_sums[wid] = acc;
    __syncthreads();

    if (threadIdx.x == 0) {
        float s = wave_sums[0] + wave_sums[1] + wave_sums[2] + wave_sums[3];
        float w = weight[0];
        atomicAdd(out, s * (-w / (float)(N_ROWS - 1)));
    }
}

extern "C" void kernel_launch(void* const* d_in, const int* in_sizes, int n_in,
                              void* d_out, int out_size, void* d_ws, size_t ws_size,
                              hipStream_t stream) {
    const float* factor = (const float*)d_in[0];
    const float* weight = (const float*)d_in[1];
    float* out = (float*)d_out;

    // d_out is poisoned to 0xAA before every call; zero it (async, capture-safe).
    hipMemsetAsync(out, 0, sizeof(float), stream);

    const long long total4 = (long long)(N_ROWS - 1) * D_COLS / 4;  // 32,767,500

    // 256 CUs x 8 blocks/CU (256 thr = 4 waves; 32 waves/CU) = 2048 blocks
    dim3 grid(2048), block(256);
    shifted_dot_kernel<<<grid, block, 0, stream>>>(factor, weight, out, total4);
}

// Round 2
// 685.993 us; speedup vs baseline: 1.0047x; 1.0047x over previous
//
#include <hip/hip_runtime.h>

// Problem: out = -weight * sum(factor[1:] * factor[:-1]) / (N-1)
// factor: (N=65536, D=2000) fp32 row-major  =>  sum a[k]*a[k+D], k in [0,(N-1)*D)
// Memory-bound: 524 MB @ ~6.3 TB/s => ~83 us kernel floor.
//
// Round 2: block-CONTIGUOUS partitioning (not grid-stride). The shifted
// stream y[k]=x[k+500 float4s] re-reads addresses the x stream touches 8 KB
// away. With contiguous per-block chunks both reads happen on the same CU
// within ~16 KB of stream progress -> L1/L2 hit, halving HBM fetch vs the
// grid-stride layout where the re-read landed on a different XCD's L2.

#define N_ROWS 65536
#define D_COLS 2000
#define NBLOCKS 2048
#define NTHREADS 256
#define CHUNK 16000LL  // float4s per block; 2048*16000 >= total4

__global__ __launch_bounds__(NTHREADS) void shifted_dot_kernel(
    const float* __restrict__ a,
    const float* __restrict__ weight,
    float* __restrict__ out,
    long long total4) {
    const float4* a4 = (const float4*)a;
    const long long shift4 = D_COLS / 4;  // 500 float4s = 8000 B (16B aligned)

    long long start = (long long)blockIdx.x * CHUNK;
    long long end   = start + CHUNK;
    if (end > total4) end = total4;

    float acc = 0.0f;
    for (long long k = start + threadIdx.x; k < end; k += NTHREADS) {
        float4 x = a4[k];
        float4 y = a4[k + shift4];
        acc += x.x * y.x + x.y * y.y + x.z * y.z + x.w * y.w;
    }

    // wave (64-lane) shuffle reduction
    #pragma unroll
    for (int off = 32; off > 0; off >>= 1)
        acc += __shfl_down(acc, off, 64);

    __shared__ float wave_sums[NTHREADS / 64];
    int lane = threadIdx.x & 63;
    int wid  = threadIdx.x >> 6;
    if (lane == 0) wave_sums[wid] = acc;
    __syncthreads();

    if (threadIdx.x == 0) {
        float s = wave_sums[0] + wave_sums[1] + wave_sums[2] + wave_sums[3];
        float w = weight[0];
        atomicAdd(out, s * (-w / (float)(N_ROWS - 1)));
    }
}

extern "C" void kernel_launch(void* const* d_in, const int* in_sizes, int n_in,
                              void* d_out, int out_size, void* d_ws, size_t ws_size,
                              hipStream_t stream) {
    const float* factor = (const float*)d_in[0];
    const float* weight = (const float*)d_in[1];
    float* out = (float*)d_out;

    // d_out is poisoned to 0xAA before every call; zero it (async, capture-safe).
    hipMemsetAsync(out, 0, sizeof(float), stream);

    const long long total4 = (long long)(N_ROWS - 1) * D_COLS / 4;  // 32,767,500

    dim3 grid(NBLOCKS), block(NTHREADS);
    shifted_dot_kernel<<<grid, block, 0, stream>>>(factor, weight, out, total4);
}

// Round 3
// 665.236 us; speedup vs baseline: 1.0360x; 1.0312x over previous
//
#include <hip/hip_runtime.h>

// out = -weight * sum(factor[1:] * factor[:-1]) / (N-1),  factor (65536, 2000) fp32.
//
// Round 3: column-wise single-pass. sum_d sum_n a[n][d]*a[n+1][d]: iterate down
// rows keeping the previous row-fragment in a register, so every element is
// loaded from HBM exactly ONCE (rounds 1-2 loaded each element twice; the 8KB-
// shifted re-read thrashed L1/L2 at full occupancy -> ~1.05 GB HBM traffic).
// 524 MB @ 6.3 TB/s => ~85 us kernel floor.
//
// Layout: row = 2000 floats = 500 float4 (8000 B, 16B-aligned rows since
// 8000%16==0). Block = 512 threads, threads 0..499 own float4-column t
// (byte 16t in the row): one wave's load = contiguous 1024 B, fully coalesced.
// 1024 blocks x 64-row bands (+1 halo row, 1.6% overfetch); 8 waves/block x
// 4 blocks/CU = 32 waves/CU = full occupancy.

#define N_ROWS 65536
#define D_COLS 2000
#define NBLOCKS 1024
#define NTHREADS 512
#define ROWS_PER_BLOCK 64

__global__ __launch_bounds__(NTHREADS) void shifted_dot_colwise(
    const float* __restrict__ a,
    const float* __restrict__ weight,
    float* __restrict__ out) {
    const int t = threadIdx.x;

    float4 acc = make_float4(0.f, 0.f, 0.f, 0.f);

    if (t < D_COLS / 4) {  // 500 active float4-columns
        const int r0 = blockIdx.x * ROWS_PER_BLOCK;
        int r1 = r0 + ROWS_PER_BLOCK;          // products n in [r0, r1)
        if (r1 > N_ROWS - 1) r1 = N_ROWS - 1;  // last band: 63 products

        // row n, this thread's fragment: a + n*2000 floats + 4t floats
        const float4* col = (const float4*)(a + (long long)r0 * D_COLS) + t;
        const int row4 = D_COLS / 4;  // 500 float4s per row

        float4 prev = col[0];
        #pragma unroll 4
        for (int n = r0 + 1; n <= r1; ++n) {
            col += row4;
            float4 curr = *col;
            acc.x += prev.x * curr.x;
            acc.y += prev.y * curr.y;
            acc.z += prev.z * curr.z;
            acc.w += prev.w * curr.w;
            prev = curr;
        }
    }

    float s = acc.x + acc.y + acc.z + acc.w;

    // wave (64-lane) shuffle reduction
    #pragma unroll
    for (int off = 32; off > 0; off >>= 1)
        s += __shfl_down(s, off, 64);

    __shared__ float wave_sums[NTHREADS / 64];
    int lane = t & 63;
    int wid  = t >> 6;
    if (lane == 0) wave_sums[wid] = s;
    __syncthreads();

    if (t == 0) {
        float tot = 0.f;
        #pragma unroll
        for (int i = 0; i < NTHREADS / 64; ++i) tot += wave_sums[i];
        float w = weight[0];
        atomicAdd(out, tot * (-w / (float)(N_ROWS - 1)));
    }
}

extern "C" void kernel_launch(void* const* d_in, const int* in_sizes, int n_in,
                              void* d_out, int out_size, void* d_ws, size_t ws_size,
                              hipStream_t stream) {
    const float* factor = (const float*)d_in[0];
    const float* weight = (const float*)d_in[1];
    float* out = (float*)d_out;

    // d_out is poisoned to 0xAA before every call; zero it (async, capture-safe).
    hipMemsetAsync(out, 0, sizeof(float), stream);

    dim3 grid(NBLOCKS), block(NTHREADS);
    shifted_dot_colwise<<<grid, block, 0, stream>>>(factor, weight, out);
}